// Round 7
// baseline (980.029 us; speedup 1.0000x reference)
//
#include <hip/hip_runtime.h>
#include <hip/hip_bf16.h>

__device__ __forceinline__ void loadrow8(float* r, const float* p) {
#pragma unroll
  for (int i = 0; i < 4; ++i) {
    float2 t = *(const float2*)(p + 2 * i);
    r[2 * i] = t.x; r[2 * i + 1] = t.y;
  }
}
__device__ __forceinline__ void loadrow6(float* r, const float* p) {
#pragma unroll
  for (int i = 0; i < 3; ++i) {
    float2 t = *(const float2*)(p + 2 * i);
    r[2 * i] = t.x; r[2 * i + 1] = t.y;
  }
}

// ---------------------------------------------------------------------------
// K1: conv1 (3->8, 7x7) + maxpool2 + relu. 256 thr = 16x16 pool tile.
// __launch_bounds__(256, 8): force VGPR <= 64 so the 64-reg HW allocation
// quantum (m69) gives 8 waves/SIMD instead of 4 -> stalls hidden.
// ---------------------------------------------------------------------------
__global__ __launch_bounds__(256, 8) void k1_conv_pool(
    const float* __restrict__ x, const float* __restrict__ w,
    const float* __restrict__ bias, float* __restrict__ out) {
  __shared__ float s_in[3 * 38 * 38];
  const int b = blockIdx.z;
  const int PX0 = blockIdx.x * 16, PY0 = blockIdx.y * 16;
  const int X0 = PX0 * 2, Y0 = PY0 * 2;
  const int tid = threadIdx.x;

  for (int idx = tid; idx < 3 * 38 * 38; idx += 256) {
    int c = idx / (38 * 38), rem = idx % (38 * 38);
    int iy = rem / 38, ixx = rem % 38;
    int gy = Y0 + iy, gxx = X0 + ixx;
    float v = 0.f;
    if (gy < 224 && gxx < 224) v = x[((b * 3 + c) * 224 + gy) * 224 + gxx];
    s_in[idx] = v;
  }
  __syncthreads();

  const int py = tid >> 4, px = tid & 15;
  float acc[8][4];
#pragma unroll
  for (int o = 0; o < 8; ++o)
    acc[o][0] = acc[o][1] = acc[o][2] = acc[o][3] = 0.f;

  for (int c = 0; c < 3; ++c) {
    const float* base = &s_in[c * 1444 + 2 * px];
    const float* wc = w + c * 49;
    float rows[2][8];
    loadrow8(rows[0], base + (2 * py) * 38);
#pragma unroll
    for (int ky = 0; ky < 7; ++ky) {
      loadrow8(rows[(ky + 1) & 1], base + (2 * py + ky + 1) * 38);
      const float* r0 = rows[ky & 1];
      const float* r1 = rows[(ky + 1) & 1];
#pragma unroll
      for (int kx = 0; kx < 7; ++kx) {
        float i00 = r0[kx], i01 = r0[kx + 1];
        float i10 = r1[kx], i11 = r1[kx + 1];
#pragma unroll
        for (int o = 0; o < 8; ++o) {
          float wv = wc[o * 147 + ky * 7 + kx];  // uniform -> s_load
          acc[o][0] = fmaf(i00, wv, acc[o][0]);
          acc[o][1] = fmaf(i01, wv, acc[o][1]);
          acc[o][2] = fmaf(i10, wv, acc[o][2]);
          acc[o][3] = fmaf(i11, wv, acc[o][3]);
        }
      }
    }
  }

  int opy = PY0 + py, opx = PX0 + px;
  if (opy < 109 && opx < 109) {
#pragma unroll
    for (int o = 0; o < 8; ++o) {
      float m = fmaxf(fmaxf(acc[o][0], acc[o][1]), fmaxf(acc[o][2], acc[o][3]));
      m += bias[o];
      out[((b * 8 + o) * 109 + opy) * 109 + opx] = fmaxf(m, 0.f);
    }
  }
}

// ---------------------------------------------------------------------------
// K2: conv2 (8->10, 5x5) + maxpool2 + relu. 13x13 pool tile; same
// occupancy treatment (min 8 waves/EU -> VGPR cap 64).
// ---------------------------------------------------------------------------
__global__ __launch_bounds__(192, 8) void k2_conv_pool(
    const float* __restrict__ in, const float* __restrict__ w,
    const float* __restrict__ bias, float* __restrict__ out) {
  __shared__ float s_in[8 * 30 * 30];
  const int b = blockIdx.z;
  const int PX0 = blockIdx.x * 13, PY0 = blockIdx.y * 13;
  const int X0 = PX0 * 2, Y0 = PY0 * 2;
  const int tid = threadIdx.x;

  for (int idx = tid; idx < 8 * 30 * 30; idx += 192) {
    int c = idx / 900, rem = idx % 900;
    int iy = rem / 30, ixx = rem % 30;
    s_in[idx] = in[((b * 8 + c) * 109 + Y0 + iy) * 109 + X0 + ixx];
  }
  __syncthreads();

  if (tid >= 169) return;
  const int py = tid / 13, px = tid % 13;
  float acc[10][4];
#pragma unroll
  for (int o = 0; o < 10; ++o)
    acc[o][0] = acc[o][1] = acc[o][2] = acc[o][3] = 0.f;

  for (int c = 0; c < 8; ++c) {
    const float* base = &s_in[c * 900 + 2 * px];
    const float* wc = w + c * 25;
    float rows[2][6];
    loadrow6(rows[0], base + (2 * py) * 30);
#pragma unroll
    for (int ky = 0; ky < 5; ++ky) {
      loadrow6(rows[(ky + 1) & 1], base + (2 * py + ky + 1) * 30);
      const float* r0 = rows[ky & 1];
      const float* r1 = rows[(ky + 1) & 1];
#pragma unroll
      for (int kx = 0; kx < 5; ++kx) {
        float i00 = r0[kx], i01 = r0[kx + 1];
        float i10 = r1[kx], i11 = r1[kx + 1];
#pragma unroll
        for (int o = 0; o < 10; ++o) {
          float wv = wc[o * 200 + ky * 5 + kx];  // uniform -> s_load
          acc[o][0] = fmaf(i00, wv, acc[o][0]);
          acc[o][1] = fmaf(i01, wv, acc[o][1]);
          acc[o][2] = fmaf(i10, wv, acc[o][2]);
          acc[o][3] = fmaf(i11, wv, acc[o][3]);
        }
      }
    }
  }

  int opy = PY0 + py, opx = PX0 + px;
#pragma unroll
  for (int o = 0; o < 10; ++o) {
    float m = fmaxf(fmaxf(acc[o][0], acc[o][1]), fmaxf(acc[o][2], acc[o][3]));
    m += bias[o];
    out[((b * 10 + o) * 52 + opy) * 52 + opx] = fmaxf(m, 0.f);
  }
}

// ---------------------------------------------------------------------------
// K3: fc1 split-K partial GEMM, 256 blocks x 2 chunks of 64.
// ---------------------------------------------------------------------------
__global__ __launch_bounds__(256) void k3_fc1_partial(
    const float* __restrict__ xs, const float* __restrict__ w,
    float* __restrict__ part) {
  __shared__ float sA[128 * 64];
  __shared__ float sW[64 * 33];
  const int p = blockIdx.x;
  const int tid = threadIdx.x;
  const int n = tid & 31, bg = tid >> 5;
  float acc[16];
#pragma unroll
  for (int i = 0; i < 16; ++i) acc[i] = 0.f;

  for (int ch = 0; ch < 2; ++ch) {
    const int k0 = p * 128 + ch * 64;
    __syncthreads();
    for (int idx = tid; idx < 8192; idx += 256) {
      int bb = idx >> 6, k = idx & 63;
      int gk = k0 + k;
      sA[idx] = (gk < 27040) ? xs[bb * 27040 + gk] : 0.f;
    }
    for (int idx = tid; idx < 2048; idx += 256) {
      int nn = idx >> 6, k = idx & 63;
      int gk = k0 + k;
      sW[k * 33 + nn] = (gk < 27040) ? w[nn * 27040 + gk] : 0.f;
    }
    __syncthreads();
    for (int k = 0; k < 64; k += 4) {
      float w0 = sW[(k + 0) * 33 + n];
      float w1 = sW[(k + 1) * 33 + n];
      float w2 = sW[(k + 2) * 33 + n];
      float w3 = sW[(k + 3) * 33 + n];
#pragma unroll
      for (int i = 0; i < 16; ++i) {
        float4 a = *(const float4*)&sA[(bg * 16 + i) * 64 + k];
        acc[i] = fmaf(a.x, w0, acc[i]);
        acc[i] = fmaf(a.y, w1, acc[i]);
        acc[i] = fmaf(a.z, w2, acc[i]);
        acc[i] = fmaf(a.w, w3, acc[i]);
      }
    }
  }
#pragma unroll
  for (int i = 0; i < 16; ++i)
    part[p * 4096 + (bg * 16 + i) * 32 + n] = acc[i];
}

// ---------------------------------------------------------------------------
// K4: reduce 256 partials -> h = relu(C + b1). 512 blocks, shfl-reduce.
// ---------------------------------------------------------------------------
__global__ __launch_bounds__(256) void k4_reduce(
    const float* __restrict__ part, const float* __restrict__ b1,
    float* __restrict__ h) {
  const int lane = threadIdx.x & 31;
  const int eloc = threadIdx.x >> 5;
  const int e = blockIdx.x * 8 + eloc;
  float s = 0.f;
#pragma unroll
  for (int pc = 0; pc < 8; ++pc) s += part[(pc * 32 + lane) * 4096 + e];
#pragma unroll
  for (int off = 16; off > 0; off >>= 1) s += __shfl_down(s, off, 32);
  if (lane == 0) h[e] = fmaxf(s + b1[e & 31], 0.f);
}

// ---------------------------------------------------------------------------
// K5: theta (recomputed per block) + fused affine_grid + bilinear sample.
// ---------------------------------------------------------------------------
__global__ __launch_bounds__(256) void k5_sample(
    const float* __restrict__ x, const float* __restrict__ h,
    const float* __restrict__ w2, const float* __restrict__ b2,
    float* __restrict__ out) {
  __shared__ float th[6];
  const int b = blockIdx.z;
  if (threadIdx.x < 6) {
    int j = threadIdx.x;
    float s = b2[j];
    for (int m = 0; m < 32; ++m) s = fmaf(h[b * 32 + m], w2[j * 32 + m], s);
    th[j] = s;
  }
  __syncthreads();

  const int pix = blockIdx.x * 256 + threadIdx.x;
  const int hh = pix / 224, ww = pix % 224;
  const float step = 2.0f / 223.0f;
  float gx = ww * step - 1.0f, gy = hh * step - 1.0f;
  float tx = th[0] * gx + th[1] * gy + th[2];
  float ty = th[3] * gx + th[4] * gy + th[5];
  float ix = (tx + 1.0f) * 0.5f * 223.0f;
  float iy = (ty + 1.0f) * 0.5f * 223.0f;
  float x0 = floorf(ix), y0 = floorf(iy);
  float x1 = x0 + 1.f, y1 = y0 + 1.f;
  float wx1 = ix - x0, wx0 = x1 - ix;
  float wy1 = iy - y0, wy0 = y1 - iy;
  float w00 = wx0 * wy0, w01 = wx1 * wy0, w10 = wx0 * wy1, w11 = wx1 * wy1;
  bool vx0 = (x0 >= 0.f) && (x0 <= 223.f);
  bool vx1 = (x1 >= 0.f) && (x1 <= 223.f);
  bool vy0 = (y0 >= 0.f) && (y0 <= 223.f);
  bool vy1 = (y1 >= 0.f) && (y1 <= 223.f);
  w00 = (vx0 && vy0) ? w00 : 0.f;
  w01 = (vx1 && vy0) ? w01 : 0.f;
  w10 = (vx0 && vy1) ? w10 : 0.f;
  w11 = (vx1 && vy1) ? w11 : 0.f;
  int xi0 = (int)fminf(fmaxf(x0, 0.f), 223.f);
  int xi1 = (int)fminf(fmaxf(x1, 0.f), 223.f);
  int yi0 = (int)fminf(fmaxf(y0, 0.f), 223.f);
  int yi1 = (int)fminf(fmaxf(y1, 0.f), 223.f);
#pragma unroll
  for (int c = 0; c < 3; ++c) {
    const float* img = x + (size_t)((b * 3 + c) * 224) * 224;
    float v = img[yi0 * 224 + xi0] * w00 + img[yi0 * 224 + xi1] * w01 +
              img[yi1 * 224 + xi0] * w10 + img[yi1 * 224 + xi1] * w11;
    out[((b * 3 + c) * 224 + hh) * 224 + ww] = v;
  }
}

extern "C" void kernel_launch(void* const* d_in, const int* in_sizes, int n_in,
                              void* d_out, int out_size, void* d_ws,
                              size_t ws_size, hipStream_t stream) {
  const float* x   = (const float*)d_in[0];
  const float* w1  = (const float*)d_in[1];
  const float* b1  = (const float*)d_in[2];
  const float* w2  = (const float*)d_in[3];
  const float* b2  = (const float*)d_in[4];
  const float* fw1 = (const float*)d_in[5];
  const float* fb1 = (const float*)d_in[6];
  const float* fw2 = (const float*)d_in[7];
  const float* fb2 = (const float*)d_in[8];
  float* out = (float*)d_out;

  float* ws   = (float*)d_ws;
  float* out1 = ws;                    // [128,8,109,109] = 12,166,144 f32
  float* xs   = out1 + 12166144;       // [128,10,52,52]  =  3,461,120 f32
  float* part = xs + 3461120;          // [256,128,32]    =  1,048,576 f32
  float* hbuf = part + 1048576;        // [128,32]        =      4,096 f32

  k1_conv_pool<<<dim3(7, 7, 128), 256, 0, stream>>>(x, w1, b1, out1);
  k2_conv_pool<<<dim3(4, 4, 128), 192, 0, stream>>>(out1, w2, b2, xs);
  k3_fc1_partial<<<256, 256, 0, stream>>>(xs, fw1, part);
  k4_reduce<<<512, 256, 0, stream>>>(part, fb1, hbuf);
  k5_sample<<<dim3(196, 1, 128), 256, 0, stream>>>(x, hbuf, fw2, fb2, out);
}

// Round 8
// 316.552 us; speedup vs baseline: 3.0960x; 3.0960x over previous
//
#include <hip/hip_runtime.h>
#include <hip/hip_bf16.h>
#include <stdint.h>

typedef __bf16 bf16x8 __attribute__((ext_vector_type(8)));
typedef float f32x4 __attribute__((ext_vector_type(4)));

union BF8 { uint32_t u[4]; bf16x8 v; };

struct __attribute__((packed, aligned(4))) F4u { float v[4]; };

struct AB { bf16x8 hi, lo; };

// split 8 f32 -> hi/lo bf16 fragments (truncation split; lo = x - hi exact)
__device__ __forceinline__ AB split8(const float* f) {
  BF8 h, l;
#pragma unroll
  for (int p = 0; p < 4; ++p) {
    uint32_t b0 = __float_as_uint(f[2 * p]);
    uint32_t b1 = __float_as_uint(f[2 * p + 1]);
    h.u[p] = (b1 & 0xFFFF0000u) | (b0 >> 16);
    float l0 = f[2 * p]     - __uint_as_float(b0 & 0xFFFF0000u);
    float l1 = f[2 * p + 1] - __uint_as_float(b1 & 0xFFFF0000u);
    l.u[p] = (__float_as_uint(l1) & 0xFFFF0000u) |
             (__float_as_uint(l0) >> 16);
  }
  AB r; r.hi = h.v; r.lo = l.v; return r;
}

// ---------------------------------------------------------------------------
// K1: conv1 (3->8, 7x7) + maxpool2 + relu via MFMA 16x16x32 bf16 (hi/lo split).
// M = 16 conv-x, N = 16 (8 ch + pad), K = 32 = c(0..3 pad) * 8 + kx(0..7 pad).
// Wave job: 16 conv-x (x0 + lane&15 rows) x 16 conv-y (acc[16]); ky-sweep
// reuses each input row in-register across up to 7 output rows.
// A-frags straight from global (2 dwordx4/lane/row), no LDS, no barriers.
// C/D layout (m89-verified): col = lane&15 = out-channel, row = (lane>>4)*4+reg
// = conv-x. Pool pairs are in-lane: regs (0,1),(2,3) x acc[2i],acc[2i+1].
// ---------------------------------------------------------------------------
__global__ __launch_bounds__(256) void k1_mfma(
    const float* __restrict__ x, const float* __restrict__ w,
    const float* __restrict__ bias, float* __restrict__ out) {
  const int b = blockIdx.z;
  const bool xedge = (blockIdx.x == 13);
  const int x0 = xedge ? 202 : blockIdx.x * 16;   // conv-x tile start (even)
  const int wid = threadIdx.x >> 6;
  const int lane = threadIdx.x & 63;
  const int y0w = blockIdx.y * 64 + wid * 16;      // conv-y start for wave
  if (y0w > 217) return;                           // fully out-of-range wave

  const int o_n = lane & 15;        // N-dim: output channel (valid < 8)
  const int grp = lane >> 4;        // K-group: input channel c (valid < 3)
  const bool bval = (o_n < 8) && (grp < 3);
  const int oc = (o_n < 8) ? o_n : 7;
  const int cc = (grp < 3) ? grp : 2;

  // ---- B-fragments: whi/wlo[ky], lane holds w[o][c][ky][kx=j], kx=7 pad 0
  BF8 zu; zu.u[0] = zu.u[1] = zu.u[2] = zu.u[3] = 0;
  const bf16x8 ZERO = zu.v;
  bf16x8 whi[7], wlo[7];
  {
    const float* wb = w + oc * 147 + cc * 49;
#pragma unroll
    for (int ky = 0; ky < 7; ++ky) {
      float t8[8];
#pragma unroll
      for (int j = 0; j < 7; ++j) t8[j] = wb[ky * 7 + j];
      t8[7] = 0.f;
      AB s = split8(t8);
      whi[ky] = bval ? s.hi : ZERO;
      wlo[ky] = bval ? s.lo : ZERO;
    }
  }

  // ---- accumulators: 16 y-rows, one 16x16 C tile each (4 f32/lane)
  f32x4 acc[16];
#pragma unroll
  for (int i = 0; i < 16; ++i) acc[i] = (f32x4){0.f, 0.f, 0.f, 0.f};

  // ---- main loop over input rows t = 0..21 (16 outputs + 6 halo)
  const float* plane = x + ((size_t)(b * 3 + cc) * 224) * 224;
  const int col0 = x0 + (lane & 15);  // A-row m = lane&15
#pragma unroll
  for (int t = 0; t < 22; ++t) {
    const int trow0 = y0w + t;
    const int trow = (trow0 < 223) ? trow0 : 223;  // clamp (feeds masked rows)
    const float* rowp = plane + (size_t)trow * 224;
    float fr[8];
    if (!xedge) {
      F4u q0 = *(const F4u*)(rowp + col0);
      F4u q1 = *(const F4u*)(rowp + col0 + 4);
#pragma unroll
      for (int j = 0; j < 4; ++j) { fr[j] = q0.v[j]; fr[4 + j] = q1.v[j]; }
    } else {
#pragma unroll
      for (int j = 0; j < 8; ++j) {
        int cj = col0 + j; cj = (cj < 223) ? cj : 223;  // kx=7 pad (w=0)
        fr[j] = rowp[cj];
      }
    }
    AB a = split8(fr);
#pragma unroll
    for (int ky = 0; ky < 7; ++ky) {
      const int yl = t - ky;
      if (yl >= 0 && yl < 16) {
        acc[yl] = __builtin_amdgcn_mfma_f32_16x16x32_bf16(a.hi, whi[ky], acc[yl], 0, 0, 0);
        acc[yl] = __builtin_amdgcn_mfma_f32_16x16x32_bf16(a.hi, wlo[ky], acc[yl], 0, 0, 0);
        acc[yl] = __builtin_amdgcn_mfma_f32_16x16x32_bf16(a.lo, whi[ky], acc[yl], 0, 0, 0);
      }
    }
  }

  // ---- epilogue: 2x2 maxpool + bias + relu, in-lane
  if (o_n < 8) {
    const float bs = bias[o_n];
    const int pxb = x0 / 2 + 2 * grp;   // pooled-x base for this lane group
    const int pyb = y0w / 2;
#pragma unroll
    for (int i = 0; i < 8; ++i) {
      const int py = pyb + i;
      if (py <= 108) {
        f32x4 A0 = acc[2 * i], A1 = acc[2 * i + 1];
        float m0 = fmaxf(fmaxf(A0[0], A0[1]), fmaxf(A1[0], A1[1])) + bs;
        float m1 = fmaxf(fmaxf(A0[2], A0[3]), fmaxf(A1[2], A1[3])) + bs;
        float* op = out + ((size_t)(b * 8 + o_n) * 109 + py) * 109 + pxb;
        op[0] = fmaxf(m0, 0.f);
        op[1] = fmaxf(m1, 0.f);
      }
    }
  }
}

__device__ __forceinline__ void loadrow6(float* r, const float* p) {
#pragma unroll
  for (int i = 0; i < 3; ++i) {
    float2 t = *(const float2*)(p + 2 * i);
    r[2 * i] = t.x; r[2 * i + 1] = t.y;
  }
}

// ---------------------------------------------------------------------------
// K2: conv2 (8->10, 5x5) + maxpool2 + relu. 13x13 pool tile, scalar weights
// (R2-proven config, plain launch bounds).
// ---------------------------------------------------------------------------
__global__ __launch_bounds__(192) void k2_conv_pool(
    const float* __restrict__ in, const float* __restrict__ w,
    const float* __restrict__ bias, float* __restrict__ out) {
  __shared__ float s_in[8 * 30 * 30];
  const int b = blockIdx.z;
  const int PX0 = blockIdx.x * 13, PY0 = blockIdx.y * 13;
  const int X0 = PX0 * 2, Y0 = PY0 * 2;
  const int tid = threadIdx.x;

  for (int idx = tid; idx < 8 * 30 * 30; idx += 192) {
    int c = idx / 900, rem = idx % 900;
    int iy = rem / 30, ixx = rem % 30;
    s_in[idx] = in[((b * 8 + c) * 109 + Y0 + iy) * 109 + X0 + ixx];
  }
  __syncthreads();

  if (tid >= 169) return;
  const int py = tid / 13, px = tid % 13;
  float acc[10][4];
#pragma unroll
  for (int o = 0; o < 10; ++o)
    acc[o][0] = acc[o][1] = acc[o][2] = acc[o][3] = 0.f;

  for (int c = 0; c < 8; ++c) {
    const float* base = &s_in[c * 900 + 2 * px];
    const float* wc = w + c * 25;
    float rows[2][6];
    loadrow6(rows[0], base + (2 * py) * 30);
#pragma unroll
    for (int ky = 0; ky < 5; ++ky) {
      loadrow6(rows[(ky + 1) & 1], base + (2 * py + ky + 1) * 30);
      const float* r0 = rows[ky & 1];
      const float* r1 = rows[(ky + 1) & 1];
#pragma unroll
      for (int kx = 0; kx < 5; ++kx) {
        float i00 = r0[kx], i01 = r0[kx + 1];
        float i10 = r1[kx], i11 = r1[kx + 1];
#pragma unroll
        for (int o = 0; o < 10; ++o) {
          float wv = wc[o * 200 + ky * 5 + kx];  // uniform -> s_load
          acc[o][0] = fmaf(i00, wv, acc[o][0]);
          acc[o][1] = fmaf(i01, wv, acc[o][1]);
          acc[o][2] = fmaf(i10, wv, acc[o][2]);
          acc[o][3] = fmaf(i11, wv, acc[o][3]);
        }
      }
    }
  }

  int opy = PY0 + py, opx = PX0 + px;
#pragma unroll
  for (int o = 0; o < 10; ++o) {
    float m = fmaxf(fmaxf(acc[o][0], acc[o][1]), fmaxf(acc[o][2], acc[o][3]));
    m += bias[o];
    out[((b * 10 + o) * 52 + opy) * 52 + opx] = fmaxf(m, 0.f);
  }
}

// ---------------------------------------------------------------------------
// K3: fc1 split-K partial GEMM, 256 blocks x 2 chunks of 64.
// ---------------------------------------------------------------------------
__global__ __launch_bounds__(256) void k3_fc1_partial(
    const float* __restrict__ xs, const float* __restrict__ w,
    float* __restrict__ part) {
  __shared__ float sA[128 * 64];
  __shared__ float sW[64 * 33];
  const int p = blockIdx.x;
  const int tid = threadIdx.x;
  const int n = tid & 31, bg = tid >> 5;
  float acc[16];
#pragma unroll
  for (int i = 0; i < 16; ++i) acc[i] = 0.f;

  for (int ch = 0; ch < 2; ++ch) {
    const int k0 = p * 128 + ch * 64;
    __syncthreads();
    for (int idx = tid; idx < 8192; idx += 256) {
      int bb = idx >> 6, k = idx & 63;
      int gk = k0 + k;
      sA[idx] = (gk < 27040) ? xs[bb * 27040 + gk] : 0.f;
    }
    for (int idx = tid; idx < 2048; idx += 256) {
      int nn = idx >> 6, k = idx & 63;
      int gk = k0 + k;
      sW[k * 33 + nn] = (gk < 27040) ? w[nn * 27040 + gk] : 0.f;
    }
    __syncthreads();
    for (int k = 0; k < 64; k += 4) {
      float w0 = sW[(k + 0) * 33 + n];
      float w1 = sW[(k + 1) * 33 + n];
      float w2 = sW[(k + 2) * 33 + n];
      float w3 = sW[(k + 3) * 33 + n];
#pragma unroll
      for (int i = 0; i < 16; ++i) {
        float4 a = *(const float4*)&sA[(bg * 16 + i) * 64 + k];
        acc[i] = fmaf(a.x, w0, acc[i]);
        acc[i] = fmaf(a.y, w1, acc[i]);
        acc[i] = fmaf(a.z, w2, acc[i]);
        acc[i] = fmaf(a.w, w3, acc[i]);
      }
    }
  }
#pragma unroll
  for (int i = 0; i < 16; ++i)
    part[p * 4096 + (bg * 16 + i) * 32 + n] = acc[i];
}

// ---------------------------------------------------------------------------
// K4: reduce 256 partials -> h = relu(C + b1). 512 blocks, shfl-reduce.
// ---------------------------------------------------------------------------
__global__ __launch_bounds__(256) void k4_reduce(
    const float* __restrict__ part, const float* __restrict__ b1,
    float* __restrict__ h) {
  const int lane = threadIdx.x & 31;
  const int eloc = threadIdx.x >> 5;
  const int e = blockIdx.x * 8 + eloc;
  float s = 0.f;
#pragma unroll
  for (int pc = 0; pc < 8; ++pc) s += part[(pc * 32 + lane) * 4096 + e];
#pragma unroll
  for (int off = 16; off > 0; off >>= 1) s += __shfl_down(s, off, 32);
  if (lane == 0) h[e] = fmaxf(s + b1[e & 31], 0.f);
}

// ---------------------------------------------------------------------------
// K5: theta (recomputed per block) + fused affine_grid + bilinear sample.
// ---------------------------------------------------------------------------
__global__ __launch_bounds__(256) void k5_sample(
    const float* __restrict__ x, const float* __restrict__ h,
    const float* __restrict__ w2, const float* __restrict__ b2,
    float* __restrict__ out) {
  __shared__ float th[6];
  const int b = blockIdx.z;
  if (threadIdx.x < 6) {
    int j = threadIdx.x;
    float s = b2[j];
    for (int m = 0; m < 32; ++m) s = fmaf(h[b * 32 + m], w2[j * 32 + m], s);
    th[j] = s;
  }
  __syncthreads();

  const int pix = blockIdx.x * 256 + threadIdx.x;
  const int hh = pix / 224, ww = pix % 224;
  const float step = 2.0f / 223.0f;
  float gx = ww * step - 1.0f, gy = hh * step - 1.0f;
  float tx = th[0] * gx + th[1] * gy + th[2];
  float ty = th[3] * gx + th[4] * gy + th[5];
  float ix = (tx + 1.0f) * 0.5f * 223.0f;
  float iy = (ty + 1.0f) * 0.5f * 223.0f;
  float x0 = floorf(ix), y0 = floorf(iy);
  float x1 = x0 + 1.f, y1 = y0 + 1.f;
  float wx1 = ix - x0, wx0 = x1 - ix;
  float wy1 = iy - y0, wy0 = y1 - iy;
  float w00 = wx0 * wy0, w01 = wx1 * wy0, w10 = wx0 * wy1, w11 = wx1 * wy1;
  bool vx0 = (x0 >= 0.f) && (x0 <= 223.f);
  bool vx1 = (x1 >= 0.f) && (x1 <= 223.f);
  bool vy0 = (y0 >= 0.f) && (y0 <= 223.f);
  bool vy1 = (y1 >= 0.f) && (y1 <= 223.f);
  w00 = (vx0 && vy0) ? w00 : 0.f;
  w01 = (vx1 && vy0) ? w01 : 0.f;
  w10 = (vx0 && vy1) ? w10 : 0.f;
  w11 = (vx1 && vy1) ? w11 : 0.f;
  int xi0 = (int)fminf(fmaxf(x0, 0.f), 223.f);
  int xi1 = (int)fminf(fmaxf(x1, 0.f), 223.f);
  int yi0 = (int)fminf(fmaxf(y0, 0.f), 223.f);
  int yi1 = (int)fminf(fmaxf(y1, 0.f), 223.f);
#pragma unroll
  for (int c = 0; c < 3; ++c) {
    const float* img = x + (size_t)((b * 3 + c) * 224) * 224;
    float v = img[yi0 * 224 + xi0] * w00 + img[yi0 * 224 + xi1] * w01 +
              img[yi1 * 224 + xi0] * w10 + img[yi1 * 224 + xi1] * w11;
    out[((b * 3 + c) * 224 + hh) * 224 + ww] = v;
  }
}

extern "C" void kernel_launch(void* const* d_in, const int* in_sizes, int n_in,
                              void* d_out, int out_size, void* d_ws,
                              size_t ws_size, hipStream_t stream) {
  const float* x   = (const float*)d_in[0];
  const float* w1  = (const float*)d_in[1];
  const float* b1  = (const float*)d_in[2];
  const float* w2  = (const float*)d_in[3];
  const float* b2  = (const float*)d_in[4];
  const float* fw1 = (const float*)d_in[5];
  const float* fb1 = (const float*)d_in[6];
  const float* fw2 = (const float*)d_in[7];
  const float* fb2 = (const float*)d_in[8];
  float* out = (float*)d_out;

  float* ws   = (float*)d_ws;
  float* out1 = ws;                    // [128,8,109,109] = 12,166,144 f32
  float* xs   = out1 + 12166144;       // [128,10,52,52]  =  3,461,120 f32
  float* part = xs + 3461120;          // [256,128,32]    =  1,048,576 f32
  float* hbuf = part + 1048576;        // [128,32]        =      4,096 f32

  k1_mfma<<<dim3(14, 4, 128), 256, 0, stream>>>(x, w1, b1, out1);
  k2_conv_pool<<<dim3(4, 4, 128), 192, 0, stream>>>(out1, w2, b2, xs);
  k3_fc1_partial<<<256, 256, 0, stream>>>(xs, fw1, part);
  k4_reduce<<<512, 256, 0, stream>>>(part, fb1, hbuf);
  k5_sample<<<dim3(196, 1, 128), 256, 0, stream>>>(x, hbuf, fw2, fb2, out);
}

// Round 9
// 260.762 us; speedup vs baseline: 3.7583x; 1.2140x over previous
//
#include <hip/hip_runtime.h>
#include <hip/hip_bf16.h>
#include <stdint.h>

typedef __bf16 bf16x8 __attribute__((ext_vector_type(8)));
typedef float f32x4 __attribute__((ext_vector_type(4)));
typedef unsigned long long u64;

union BFrag { uint32_t u[4]; u64 q[2]; bf16x8 v; };

// truncation split: f = hi + lo (+ O(2^-16) on lo)
__device__ __forceinline__ void split1(float f, uint32_t& hi, uint32_t& lo) {
  uint32_t b = __float_as_uint(f);
  hi = b >> 16;
  float fl = f - __uint_as_float(b & 0xFFFF0000u);
  lo = __float_as_uint(fl) >> 16;
}

// ---------------------------------------------------------------------------
// K0: pack conv1 weights into MFMA B-fragments (hi/lo bf16).
// Index id = ((jf*4 + g)*16 + n)*8 + j ; n=(o,half), k-slot=(kx=2g+(j>>2),
// c=j&3), ky = jf - half. Invalid (c==3 | kx==7 | ky out of range) -> 0.
// ---------------------------------------------------------------------------
__global__ __launch_bounds__(256) void k0_wprep(
    const float* __restrict__ w1, unsigned short* __restrict__ wpHi,
    unsigned short* __restrict__ wpLo) {
  int id = blockIdx.x * 256 + threadIdx.x;
  if (id >= 4096) return;
  int j = id & 7, n = (id >> 3) & 15, g = (id >> 7) & 3, jf = id >> 9;
  int o = n & 7, half = n >> 3;
  int ky = jf - half, c = j & 3, kx = 2 * g + (j >> 2);
  float f = 0.f;
  if (c < 3 && kx < 7 && ky >= 0 && ky < 7)
    f = w1[o * 147 + c * 49 + ky * 7 + kx];
  uint32_t h, l;
  split1(f, h, l);
  wpHi[id] = (unsigned short)h;
  wpLo[id] = (unsigned short)l;
}

// ---------------------------------------------------------------------------
// K1: conv1 (3->8, 7x7) + maxpool2 + relu via MFMA 16x16x32 bf16.
// N = 8ch x 2ky (pairing): acc[i] covers output rows (2i, 2i+1).
// Input staged in LDS channels-last bf16 hi/lo (split once per element);
// A k-map = (kx=2g+(j>>2), c=j&3) -> 8 consecutive shorts, 2x ds_read_b64.
// C/D: col=lane&15=(o,half), row=(lane>>4)*4+reg = conv-x (m89-verified).
// ---------------------------------------------------------------------------
__global__ __launch_bounds__(256) void k1_mfma(
    const float* __restrict__ x, const unsigned short* __restrict__ wpHi,
    const unsigned short* __restrict__ wpLo, const float* __restrict__ bias,
    float* __restrict__ out) {
  __shared__ unsigned short sH[2 * 70 * 24 * 4];  // [plane][row 70][col 24][c 4]
  const int b = blockIdx.z;
  const int x0 = blockIdx.x * 16;
  const int y0blk = blockIdx.y * 64;
  const int tid = threadIdx.x;
  const int lane = tid & 63, wid = tid >> 6;
  const int n = lane & 15, g = lane >> 4;

  // ---- B fragments: 8 jf x (hi,lo), 16B aligned contiguous loads
  BFrag bhi[8], blo[8];
#pragma unroll
  for (int jf = 0; jf < 8; ++jf) {
    uint4 th = *(const uint4*)&wpHi[((jf * 4 + g) * 16 + n) * 8];
    uint4 tl = *(const uint4*)&wpLo[((jf * 4 + g) * 16 + n) * 8];
    bhi[jf].u[0] = th.x; bhi[jf].u[1] = th.y;
    bhi[jf].u[2] = th.z; bhi[jf].u[3] = th.w;
    blo[jf].u[0] = tl.x; blo[jf].u[1] = tl.y;
    blo[jf].u[2] = tl.z; blo[jf].u[3] = tl.w;
  }

  // ---- stage input tile: rows y0blk..+69, cols x0..+23, split f32->hi/lo
  const float* xb = x + (size_t)b * 3 * 50176;
  for (int pos = tid; pos < 70 * 24; pos += 256) {
    int row = pos / 24, col = pos % 24;
    int gy = y0blk + row; gy = gy < 223 ? gy : 223;
    int gx = x0 + col;    gx = gx < 223 ? gx : 223;
    const float* p = xb + (size_t)gy * 224 + gx;
    uint32_t h0, l0, h1, l1, h2, l2;
    split1(p[0], h0, l0);
    split1(p[50176], h1, l1);
    split1(p[100352], h2, l2);
    u64 hq = (u64)(h0 | (h1 << 16)) | ((u64)h2 << 32);
    u64 lq = (u64)(l0 | (l1 << 16)) | ((u64)l2 << 32);
    *(u64*)&sH[pos * 4] = hq;           // hi plane
    *(u64*)&sH[6720 + pos * 4] = lq;    // lo plane
  }
  __syncthreads();

  const int y0w = y0blk + wid * 16;
  if (y0w <= 217) {
    f32x4 acc[8];
#pragma unroll
    for (int i = 0; i < 8; ++i) acc[i] = (f32x4){0.f, 0.f, 0.f, 0.f};

    const int mg = n + 2 * g;  // LDS col = conv-x offset (lane&15) + 2g
    const int rbase = wid * 16;
#pragma unroll
    for (int t = 0; t < 22; ++t) {
      const int s0 = ((rbase + t) * 24 + mg) * 4;
      BFrag ah, al;
      ah.q[0] = *(const u64*)&sH[s0];
      ah.q[1] = *(const u64*)&sH[s0 + 4];
      al.q[0] = *(const u64*)&sH[6720 + s0];
      al.q[1] = *(const u64*)&sH[6720 + s0 + 4];
#pragma unroll
      for (int i = 0; i < 8; ++i) {
        const int jf = t - 2 * i;
        if (jf >= 0 && jf < 8) {
          acc[i] = __builtin_amdgcn_mfma_f32_16x16x32_bf16(ah.v, bhi[jf].v, acc[i], 0, 0, 0);
          acc[i] = __builtin_amdgcn_mfma_f32_16x16x32_bf16(ah.v, blo[jf].v, acc[i], 0, 0, 0);
          acc[i] = __builtin_amdgcn_mfma_f32_16x16x32_bf16(al.v, bhi[jf].v, acc[i], 0, 0, 0);
        }
      }
    }

    // ---- epilogue: pool-x in-lane (reg pairs), pool-y via shfl_xor(8)
    const int o = n & 7;
    const float bs = bias[o];
    const int px0 = x0 / 2 + 2 * g;
    const int py0 = y0w / 2;
#pragma unroll
    for (int i = 0; i < 8; ++i) {
      float v0 = fmaxf(acc[i][0], acc[i][1]);
      float v1 = fmaxf(acc[i][2], acc[i][3]);
      float p0 = __shfl_xor(v0, 8, 64);
      float p1 = __shfl_xor(v1, 8, 64);
      const int py = py0 + i;
      if (n < 8 && py < 109) {
        float m0 = fmaxf(v0, p0) + bs;
        float m1 = fmaxf(v1, p1) + bs;
        float* op = out + ((size_t)(b * 8 + o) * 109 + py) * 109 + px0;
        if (px0 < 109)     op[0] = fmaxf(m0, 0.f);
        if (px0 + 1 < 109) op[1] = fmaxf(m1, 0.f);
      }
    }
  }
}

__device__ __forceinline__ void loadrow6(float* r, const float* p) {
#pragma unroll
  for (int i = 0; i < 3; ++i) {
    float2 t = *(const float2*)(p + 2 * i);
    r[2 * i] = t.x; r[2 * i + 1] = t.y;
  }
}

// ---------------------------------------------------------------------------
// K2: conv2 (8->10, 5x5) + maxpool2 + relu. 13x13 pool tile, scalar weights.
// ---------------------------------------------------------------------------
__global__ __launch_bounds__(192) void k2_conv_pool(
    const float* __restrict__ in, const float* __restrict__ w,
    const float* __restrict__ bias, float* __restrict__ out) {
  __shared__ float s_in[8 * 30 * 30];
  const int b = blockIdx.z;
  const int PX0 = blockIdx.x * 13, PY0 = blockIdx.y * 13;
  const int X0 = PX0 * 2, Y0 = PY0 * 2;
  const int tid = threadIdx.x;

  for (int idx = tid; idx < 8 * 30 * 30; idx += 192) {
    int c = idx / 900, rem = idx % 900;
    int iy = rem / 30, ixx = rem % 30;
    s_in[idx] = in[((b * 8 + c) * 109 + Y0 + iy) * 109 + X0 + ixx];
  }
  __syncthreads();

  if (tid >= 169) return;
  const int py = tid / 13, px = tid % 13;
  float acc[10][4];
#pragma unroll
  for (int o = 0; o < 10; ++o)
    acc[o][0] = acc[o][1] = acc[o][2] = acc[o][3] = 0.f;

  for (int c = 0; c < 8; ++c) {
    const float* base = &s_in[c * 900 + 2 * px];
    const float* wc = w + c * 25;
    float rows[2][6];
    loadrow6(rows[0], base + (2 * py) * 30);
#pragma unroll
    for (int ky = 0; ky < 5; ++ky) {
      loadrow6(rows[(ky + 1) & 1], base + (2 * py + ky + 1) * 30);
      const float* r0 = rows[ky & 1];
      const float* r1 = rows[(ky + 1) & 1];
#pragma unroll
      for (int kx = 0; kx < 5; ++kx) {
        float i00 = r0[kx], i01 = r0[kx + 1];
        float i10 = r1[kx], i11 = r1[kx + 1];
#pragma unroll
        for (int o = 0; o < 10; ++o) {
          float wv = wc[o * 200 + ky * 5 + kx];
          acc[o][0] = fmaf(i00, wv, acc[o][0]);
          acc[o][1] = fmaf(i01, wv, acc[o][1]);
          acc[o][2] = fmaf(i10, wv, acc[o][2]);
          acc[o][3] = fmaf(i11, wv, acc[o][3]);
        }
      }
    }
  }

  int opy = PY0 + py, opx = PX0 + px;
#pragma unroll
  for (int o = 0; o < 10; ++o) {
    float m = fmaxf(fmaxf(acc[o][0], acc[o][1]), fmaxf(acc[o][2], acc[o][3]));
    m += bias[o];
    out[((b * 10 + o) * 52 + opy) * 52 + opx] = fmaxf(m, 0.f);
  }
}

// ---------------------------------------------------------------------------
// K3: fc1 split-K partial GEMM, 256 blocks x 2 chunks of 64.
// ---------------------------------------------------------------------------
__global__ __launch_bounds__(256) void k3_fc1_partial(
    const float* __restrict__ xs, const float* __restrict__ w,
    float* __restrict__ part) {
  __shared__ float sA[128 * 64];
  __shared__ float sW[64 * 33];
  const int p = blockIdx.x;
  const int tid = threadIdx.x;
  const int n = tid & 31, bg = tid >> 5;
  float acc[16];
#pragma unroll
  for (int i = 0; i < 16; ++i) acc[i] = 0.f;

  for (int ch = 0; ch < 2; ++ch) {
    const int k0 = p * 128 + ch * 64;
    __syncthreads();
    for (int idx = tid; idx < 8192; idx += 256) {
      int bb = idx >> 6, k = idx & 63;
      int gk = k0 + k;
      sA[idx] = (gk < 27040) ? xs[bb * 27040 + gk] : 0.f;
    }
    for (int idx = tid; idx < 2048; idx += 256) {
      int nn = idx >> 6, k = idx & 63;
      int gk = k0 + k;
      sW[k * 33 + nn] = (gk < 27040) ? w[nn * 27040 + gk] : 0.f;
    }
    __syncthreads();
    for (int k = 0; k < 64; k += 4) {
      float w0 = sW[(k + 0) * 33 + n];
      float w1 = sW[(k + 1) * 33 + n];
      float w2 = sW[(k + 2) * 33 + n];
      float w3 = sW[(k + 3) * 33 + n];
#pragma unroll
      for (int i = 0; i < 16; ++i) {
        float4 a = *(const float4*)&sA[(bg * 16 + i) * 64 + k];
        acc[i] = fmaf(a.x, w0, acc[i]);
        acc[i] = fmaf(a.y, w1, acc[i]);
        acc[i] = fmaf(a.z, w2, acc[i]);
        acc[i] = fmaf(a.w, w3, acc[i]);
      }
    }
  }
#pragma unroll
  for (int i = 0; i < 16; ++i)
    part[p * 4096 + (bg * 16 + i) * 32 + n] = acc[i];
}

// ---------------------------------------------------------------------------
// K4: reduce 256 partials -> h = relu(C + b1). 512 blocks, shfl-reduce.
// ---------------------------------------------------------------------------
__global__ __launch_bounds__(256) void k4_reduce(
    const float* __restrict__ part, const float* __restrict__ b1,
    float* __restrict__ h) {
  const int lane = threadIdx.x & 31;
  const int eloc = threadIdx.x >> 5;
  const int e = blockIdx.x * 8 + eloc;
  float s = 0.f;
#pragma unroll
  for (int pc = 0; pc < 8; ++pc) s += part[(pc * 32 + lane) * 4096 + e];
#pragma unroll
  for (int off = 16; off > 0; off >>= 1) s += __shfl_down(s, off, 32);
  if (lane == 0) h[e] = fmaxf(s + b1[e & 31], 0.f);
}

// ---------------------------------------------------------------------------
// K5: theta (recomputed per block) + fused affine_grid + bilinear sample.
// ---------------------------------------------------------------------------
__global__ __launch_bounds__(256) void k5_sample(
    const float* __restrict__ x, const float* __restrict__ h,
    const float* __restrict__ w2, const float* __restrict__ b2,
    float* __restrict__ out) {
  __shared__ float th[6];
  const int b = blockIdx.z;
  if (threadIdx.x < 6) {
    int j = threadIdx.x;
    float s = b2[j];
    for (int m = 0; m < 32; ++m) s = fmaf(h[b * 32 + m], w2[j * 32 + m], s);
    th[j] = s;
  }
  __syncthreads();

  const int pix = blockIdx.x * 256 + threadIdx.x;
  const int hh = pix / 224, ww = pix % 224;
  const float step = 2.0f / 223.0f;
  float gx = ww * step - 1.0f, gy = hh * step - 1.0f;
  float tx = th[0] * gx + th[1] * gy + th[2];
  float ty = th[3] * gx + th[4] * gy + th[5];
  float ix = (tx + 1.0f) * 0.5f * 223.0f;
  float iy = (ty + 1.0f) * 0.5f * 223.0f;
  float x0 = floorf(ix), y0 = floorf(iy);
  float x1 = x0 + 1.f, y1 = y0 + 1.f;
  float wx1 = ix - x0, wx0 = x1 - ix;
  float wy1 = iy - y0, wy0 = y1 - iy;
  float w00 = wx0 * wy0, w01 = wx1 * wy0, w10 = wx0 * wy1, w11 = wx1 * wy1;
  bool vx0 = (x0 >= 0.f) && (x0 <= 223.f);
  bool vx1 = (x1 >= 0.f) && (x1 <= 223.f);
  bool vy0 = (y0 >= 0.f) && (y0 <= 223.f);
  bool vy1 = (y1 >= 0.f) && (y1 <= 223.f);
  w00 = (vx0 && vy0) ? w00 : 0.f;
  w01 = (vx1 && vy0) ? w01 : 0.f;
  w10 = (vx0 && vy1) ? w10 : 0.f;
  w11 = (vx1 && vy1) ? w11 : 0.f;
  int xi0 = (int)fminf(fmaxf(x0, 0.f), 223.f);
  int xi1 = (int)fminf(fmaxf(x1, 0.f), 223.f);
  int yi0 = (int)fminf(fmaxf(y0, 0.f), 223.f);
  int yi1 = (int)fminf(fmaxf(y1, 0.f), 223.f);
#pragma unroll
  for (int c = 0; c < 3; ++c) {
    const float* img = x + (size_t)((b * 3 + c) * 224) * 224;
    float v = img[yi0 * 224 + xi0] * w00 + img[yi0 * 224 + xi1] * w01 +
              img[yi1 * 224 + xi0] * w10 + img[yi1 * 224 + xi1] * w11;
    out[((b * 3 + c) * 224 + hh) * 224 + ww] = v;
  }
}

extern "C" void kernel_launch(void* const* d_in, const int* in_sizes, int n_in,
                              void* d_out, int out_size, void* d_ws,
                              size_t ws_size, hipStream_t stream) {
  const float* x   = (const float*)d_in[0];
  const float* w1  = (const float*)d_in[1];
  const float* b1  = (const float*)d_in[2];
  const float* w2  = (const float*)d_in[3];
  const float* b2  = (const float*)d_in[4];
  const float* fw1 = (const float*)d_in[5];
  const float* fb1 = (const float*)d_in[6];
  const float* fw2 = (const float*)d_in[7];
  const float* fb2 = (const float*)d_in[8];
  float* out = (float*)d_out;

  float* ws   = (float*)d_ws;
  float* out1 = ws;                    // [128,8,109,109] = 12,166,144 f32
  float* xs   = out1 + 12166144;       // [128,10,52,52]  =  3,461,120 f32
  float* part = xs + 3461120;          // [256,128,32]    =  1,048,576 f32
  float* hbuf = part + 1048576;        // [128,32]        =      4,096 f32
  unsigned short* wpHi = (unsigned short*)(hbuf + 4096);  // 4096 us (16B-align)
  unsigned short* wpLo = wpHi + 4096;                     // 4096 us

  k0_wprep<<<16, 256, 0, stream>>>(w1, wpHi, wpLo);
  k1_mfma<<<dim3(14, 4, 128), 256, 0, stream>>>(x, wpHi, wpLo, b1, out1);
  k2_conv_pool<<<dim3(4, 4, 128), 192, 0, stream>>>(out1, w2, b2, xs);
  k3_fc1_partial<<<256, 256, 0, stream>>>(xs, fw1, part);
  k4_reduce<<<512, 256, 0, stream>>>(part, fb1, hbuf);
  k5_sample<<<dim3(196, 1, 128), 256, 0, stream>>>(x, hbuf, fw2, fb2, out);
}